// Round 1
// baseline (338.839 us; speedup 1.0000x reference)
//
#include <hip/hip_runtime.h>
#include <hip/hip_bf16.h>

#define NROWS 16384
#define DIN   4096
#define DOUT  4096
#define RNK   64
#define EPSF  1e-7f

typedef float  f32x4  __attribute__((ext_vector_type(4)));
typedef __bf16 bf16x4 __attribute__((ext_vector_type(4)));
typedef __bf16 bf16x8 __attribute__((ext_vector_type(8)));

#define LP 72  // LDS row pitch in bf16 (144 B: breaks power-of-2 bank stride, keeps 16B align)

__device__ __forceinline__ bf16x4 cvt4(f32x4 v) {
    bf16x4 r;
    r.x = (__bf16)v.x; r.y = (__bf16)v.y; r.z = (__bf16)v.z; r.w = (__bf16)v.w;
    return r;
}

// ---------------------------------------------------------------------------
// K1: s1[m][r] = sinh(||x_m||)/||x_m|| * sum_k x[m][k] * Aw[r][k]
// 64-row tile per block, 8 waves: wave w -> rows (w&3)*16, cols (w>>2)*32..+31
// Reg-staged double-buffered global->LDS(bf16); row sumsq fused into staging.
// ---------------------------------------------------------------------------
__global__ __launch_bounds__(512, 1)
void k1_expmap_gemm1(const float* __restrict__ x, const float* __restrict__ Aw,
                     float* __restrict__ s1) {
    __shared__ __bf16 xs[64][LP];
    __shared__ __bf16 as[64][LP];
    __shared__ float rowss[64];

    const int t = threadIdx.x;
    const int l = t & 63;
    const int w = t >> 6;
    const int brow = blockIdx.x * 64;
    if (t < 64) rowss[t] = 0.f;

    // staging map: thread t covers (srow, srow+32) x 4 floats at scol
    const int srow = t >> 4;           // 0..31
    const int scol = (t & 15) * 4;     // 0..60
    const size_t xb0 = (size_t)(brow + srow) * DIN + scol;
    const size_t xb1 = (size_t)(brow + srow + 32) * DIN + scol;
    const size_t ab0 = (size_t)srow * DIN + scol;
    const size_t ab1 = (size_t)(srow + 32) * DIN + scol;

    const int m0   = (w & 3) * 16;
    const int n0   = (w >> 2) * 32;
    const int frow = l & 15;
    const int koff = (l >> 4) * 8;

    f32x4 rx0[2], rx1[2], ra0[2], ra1[2];
    float ssq0 = 0.f, ssq1 = 0.f;
    f32x4 acc0 = {0.f, 0.f, 0.f, 0.f};
    f32x4 acc1 = {0.f, 0.f, 0.f, 0.f};

    // prologue: load K-tile 0
    rx0[0] = *(const f32x4*)&x[xb0];
    rx1[0] = *(const f32x4*)&x[xb1];
    ra0[0] = *(const f32x4*)&Aw[ab0];
    ra1[0] = *(const f32x4*)&Aw[ab1];

    const int NT = DIN / 64;  // 64 K-tiles
    int cur = 0;
    for (int kt = 0; kt < NT; ++kt) {
        const int nxt = cur ^ 1;
        if (kt + 1 < NT) {  // issue next tile's loads (in flight across compute)
            const size_t o = (size_t)(kt + 1) * 64;
            rx0[nxt] = *(const f32x4*)&x[xb0 + o];
            rx1[nxt] = *(const f32x4*)&x[xb1 + o];
            ra0[nxt] = *(const f32x4*)&Aw[ab0 + o];
            ra1[nxt] = *(const f32x4*)&Aw[ab1 + o];
        }
        // write current tile to LDS as bf16; fuse x row-sumsq (f32, full precision)
        f32x4 v0 = rx0[cur], v1 = rx1[cur];
        ssq0 += v0.x*v0.x + v0.y*v0.y + v0.z*v0.z + v0.w*v0.w;
        ssq1 += v1.x*v1.x + v1.y*v1.y + v1.z*v1.z + v1.w*v1.w;
        *(bf16x4*)&xs[srow][scol]      = cvt4(v0);
        *(bf16x4*)&xs[srow + 32][scol] = cvt4(v1);
        *(bf16x4*)&as[srow][scol]      = cvt4(ra0[cur]);
        *(bf16x4*)&as[srow + 32][scol] = cvt4(ra1[cur]);
        __syncthreads();
        #pragma unroll
        for (int kk = 0; kk < 2; ++kk) {
            bf16x8 af = *(const bf16x8*)&xs[m0 + frow][kk * 32 + koff];
            bf16x8 b0 = *(const bf16x8*)&as[n0 + frow][kk * 32 + koff];
            bf16x8 b1 = *(const bf16x8*)&as[n0 + 16 + frow][kk * 32 + koff];
            acc0 = __builtin_amdgcn_mfma_f32_16x16x32_bf16(af, b0, acc0, 0, 0, 0);
            acc1 = __builtin_amdgcn_mfma_f32_16x16x32_bf16(af, b1, acc1, 0, 0, 0);
        }
        __syncthreads();
        cur = nxt;
    }

    atomicAdd(&rowss[srow], ssq0);
    atomicAdd(&rowss[srow + 32], ssq1);
    __syncthreads();
    if (t < 64) {
        float vn = fmaxf(sqrtf(rowss[t]), EPSF);
        rowss[t] = sinhf(vn) / vn;   // expmap0 spatial scale
    }
    __syncthreads();

    // epilogue: C/D layout col=lane&15, row=(lane>>4)*4+q  [m89/m91-verified]
    #pragma unroll
    for (int q = 0; q < 4; ++q) {
        const int row = m0 + (l >> 4) * 4 + q;
        const float sc = rowss[row];
        s1[(size_t)(brow + row) * RNK + n0 + frow]      = sc * acc0[q];
        s1[(size_t)(brow + row) * RNK + n0 + 16 + frow] = sc * acc1[q];
    }
}

// ---------------------------------------------------------------------------
// K2: s2 = s1 @ Bw^T (K=64); out = 0.25*acosh(max(sqrt(1+r^2),1+eps))/max(r,eps)*s2
// Two passes per block (norm pass, write pass); B tiles stream from L2.
// ---------------------------------------------------------------------------
__global__ __launch_bounds__(512, 1)
void k2_gemm2_logmap(const float* __restrict__ s1, const float* __restrict__ Bw,
                     float* __restrict__ out) {
    __shared__ __bf16 ss[64][LP];
    __shared__ __bf16 bs[64][LP];
    __shared__ float rowg[64];

    const int t = threadIdx.x;
    const int l = t & 63;
    const int w = t >> 6;
    const int brow = blockIdx.x * 64;
    if (t < 64) rowg[t] = 0.f;

    // stage the 64x64 s1 tile once (f32 -> bf16)
    {
        const int row = t >> 3;          // 0..63
        const int c   = (t & 7) * 8;     // 0..56
        f32x4 u0 = *(const f32x4*)&s1[(size_t)(brow + row) * RNK + c];
        f32x4 u1 = *(const f32x4*)&s1[(size_t)(brow + row) * RNK + c + 4];
        *(bf16x4*)&ss[row][c]     = cvt4(u0);
        *(bf16x4*)&ss[row][c + 4] = cvt4(u1);
    }

    const int srow = t >> 4;
    const int scol = (t & 15) * 4;
    const int m0   = (w & 3) * 16;
    const int n0   = (w >> 2) * 32;
    const int frow = l & 15;
    const int koff = (l >> 4) * 8;
    const size_t bb0 = (size_t)srow * RNK + scol;
    const size_t bb1 = (size_t)(srow + 32) * RNK + scol;

    const int NJ = DOUT / 64;  // 64 column blocks
    f32x4 rb0[2], rb1[2];
    float ssq[4] = {0.f, 0.f, 0.f, 0.f};

    // ---- pass 1: accumulate ||s2_row||^2 ----
    rb0[0] = *(const f32x4*)&Bw[bb0];
    rb1[0] = *(const f32x4*)&Bw[bb1];
    int cur = 0;
    for (int jb = 0; jb < NJ; ++jb) {
        const int nxt = cur ^ 1;
        if (jb + 1 < NJ) {
            const size_t o = (size_t)(jb + 1) * 64 * RNK;
            rb0[nxt] = *(const f32x4*)&Bw[bb0 + o];
            rb1[nxt] = *(const f32x4*)&Bw[bb1 + o];
        }
        *(bf16x4*)&bs[srow][scol]      = cvt4(rb0[cur]);
        *(bf16x4*)&bs[srow + 32][scol] = cvt4(rb1[cur]);
        __syncthreads();
        f32x4 a0 = {0.f,0.f,0.f,0.f}, a1 = {0.f,0.f,0.f,0.f};
        #pragma unroll
        for (int kk = 0; kk < 2; ++kk) {
            bf16x8 af = *(const bf16x8*)&ss[m0 + frow][kk * 32 + koff];
            bf16x8 b0 = *(const bf16x8*)&bs[n0 + frow][kk * 32 + koff];
            bf16x8 b1 = *(const bf16x8*)&bs[n0 + 16 + frow][kk * 32 + koff];
            a0 = __builtin_amdgcn_mfma_f32_16x16x32_bf16(af, b0, a0, 0, 0, 0);
            a1 = __builtin_amdgcn_mfma_f32_16x16x32_bf16(af, b1, a1, 0, 0, 0);
        }
        #pragma unroll
        for (int q = 0; q < 4; ++q) ssq[q] += a0[q]*a0[q] + a1[q]*a1[q];
        __syncthreads();
        cur = nxt;
    }
    #pragma unroll
    for (int q = 0; q < 4; ++q) {
        float v = ssq[q];
        v += __shfl_xor(v, 1);
        v += __shfl_xor(v, 2);
        v += __shfl_xor(v, 4);
        v += __shfl_xor(v, 8);
        if (frow == 0) atomicAdd(&rowg[m0 + (l >> 4) * 4 + q], v);
    }
    __syncthreads();
    if (t < 64) {
        float r2  = rowg[t];
        float r   = sqrtf(r2);
        float arg = fmaxf(sqrtf(1.f + r2), 1.f + EPSF);
        float d   = acoshf(arg);
        rowg[t] = 0.25f * d / fmaxf(r, EPSF);   // ALPHA/RANK = 0.25
    }
    __syncthreads();

    float gq[4];
    #pragma unroll
    for (int q = 0; q < 4; ++q) gq[q] = rowg[m0 + (l >> 4) * 4 + q];

    // ---- pass 2: recompute s2, scale, write ----
    rb0[0] = *(const f32x4*)&Bw[bb0];
    rb1[0] = *(const f32x4*)&Bw[bb1];
    cur = 0;
    for (int jb = 0; jb < NJ; ++jb) {
        const int nxt = cur ^ 1;
        if (jb + 1 < NJ) {
            const size_t o = (size_t)(jb + 1) * 64 * RNK;
            rb0[nxt] = *(const f32x4*)&Bw[bb0 + o];
            rb1[nxt] = *(const f32x4*)&Bw[bb1 + o];
        }
        *(bf16x4*)&bs[srow][scol]      = cvt4(rb0[cur]);
        *(bf16x4*)&bs[srow + 32][scol] = cvt4(rb1[cur]);
        __syncthreads();
        f32x4 a0 = {0.f,0.f,0.f,0.f}, a1 = {0.f,0.f,0.f,0.f};
        #pragma unroll
        for (int kk = 0; kk < 2; ++kk) {
            bf16x8 af = *(const bf16x8*)&ss[m0 + frow][kk * 32 + koff];
            bf16x8 b0 = *(const bf16x8*)&bs[n0 + frow][kk * 32 + koff];
            bf16x8 b1 = *(const bf16x8*)&bs[n0 + 16 + frow][kk * 32 + koff];
            a0 = __builtin_amdgcn_mfma_f32_16x16x32_bf16(af, b0, a0, 0, 0, 0);
            a1 = __builtin_amdgcn_mfma_f32_16x16x32_bf16(af, b1, a1, 0, 0, 0);
        }
        #pragma unroll
        for (int q = 0; q < 4; ++q) {
            const int row = m0 + (l >> 4) * 4 + q;
            const size_t ob = (size_t)(brow + row) * DOUT + (size_t)jb * 64;
            out[ob + n0 + frow]      = gq[q] * a0[q];
            out[ob + n0 + 16 + frow] = gq[q] * a1[q];
        }
        __syncthreads();
        cur = nxt;
    }
}

extern "C" void kernel_launch(void* const* d_in, const int* in_sizes, int n_in,
                              void* d_out, int out_size, void* d_ws, size_t ws_size,
                              hipStream_t stream) {
    const float* x  = (const float*)d_in[0];   // (16384, 4096)
    const float* Aw = (const float*)d_in[1];   // (64, 4096)
    const float* Bw = (const float*)d_in[2];   // (4096, 64)
    float* out = (float*)d_out;                // (16384, 4096) f32
    float* s1  = (float*)d_ws;                 // 16384*64 f32 = 4 MB scratch

    k1_expmap_gemm1<<<NROWS / 64, 512, 0, stream>>>(x, Aw, s1);
    k2_gemm2_logmap<<<NROWS / 64, 512, 0, stream>>>(s1, Bw, out);
}

// Round 2
// 169.516 us; speedup vs baseline: 1.9989x; 1.9989x over previous
//
#include <hip/hip_runtime.h>
#include <hip/hip_bf16.h>

#define NROWS 16384
#define DIN   4096
#define DOUT  4096
#define RNK   64
#define EPSF  1e-7f

typedef float  f32x4  __attribute__((ext_vector_type(4)));
typedef __bf16 bf16x4 __attribute__((ext_vector_type(4)));
typedef __bf16 bf16x8 __attribute__((ext_vector_type(8)));

__device__ __forceinline__ bf16x8 cvt8(f32x4 a, f32x4 b) {
    bf16x8 r;
    r[0]=(__bf16)a.x; r[1]=(__bf16)a.y; r[2]=(__bf16)a.z; r[3]=(__bf16)a.w;
    r[4]=(__bf16)b.x; r[5]=(__bf16)b.y; r[6]=(__bf16)b.z; r[7]=(__bf16)b.w;
    return r;
}

// ---------------------------------------------------------------------------
// K1: s1[m][r] = sinh(||x_m||)/||x_m|| * (x @ Aw^T)[m][r]   (f32 out, 4 MB)
// 32-row tiles, 512 blocks (2/CU), 512 thr, BK=128, named-reg double buffer.
// ---------------------------------------------------------------------------
#define LPK 136   // LDS pitch for BK=128 (+8 pad), 272 B rows (16B aligned)
__global__ __launch_bounds__(512, 4)
void k1_expmap_gemm1(const float* __restrict__ x, const float* __restrict__ Aw,
                     float* __restrict__ s1) {
    __shared__ __bf16 xs[32][LPK];
    __shared__ __bf16 as[64][LPK];
    __shared__ float rowss[32];

    const int t = threadIdx.x;
    const int l = t & 63;
    const int w = t >> 6;
    const int brow = blockIdx.x * 32;

    // staging maps
    const int xrow = t >> 4, xcol = (t & 15) * 8;   // x: 32x128, 8 f32/thr
    const int arow = t >> 3, acol = (t & 7) * 16;   // A: 64x128, 16 f32/thr
    const size_t xb = (size_t)(brow + xrow) * DIN + xcol;
    const size_t ab = (size_t)arow * DIN + acol;

    const int m0 = (w & 1) * 16;     // 2 m-groups
    const int n0 = (w >> 1) * 16;    // 4 n-groups
    const int frow = l & 15;
    const int koff = (l >> 4) * 8;

    float ssq = 0.f;
    f32x4 acc = {0.f, 0.f, 0.f, 0.f};

    f32x4 xA0,xA1,aA0,aA1,aA2,aA3, xB0,xB1,aB0,aB1,aB2,aB3;

    auto load = [&](f32x4&x0,f32x4&x1,f32x4&A0,f32x4&A1,f32x4&A2,f32x4&A3,int kt){
        const size_t o = (size_t)kt * 128;
        x0 = *(const f32x4*)&x[xb + o];       x1 = *(const f32x4*)&x[xb + o + 4];
        A0 = *(const f32x4*)&Aw[ab + o];      A1 = *(const f32x4*)&Aw[ab + o + 4];
        A2 = *(const f32x4*)&Aw[ab + o + 8];  A3 = *(const f32x4*)&Aw[ab + o + 12];
    };
    auto consume = [&](const f32x4&x0,const f32x4&x1,const f32x4&A0,
                       const f32x4&A1,const f32x4&A2,const f32x4&A3){
        ssq += x0.x*x0.x + x0.y*x0.y + x0.z*x0.z + x0.w*x0.w;
        ssq += x1.x*x1.x + x1.y*x1.y + x1.z*x1.z + x1.w*x1.w;
        *(bf16x8*)&xs[xrow][xcol]     = cvt8(x0, x1);
        *(bf16x8*)&as[arow][acol]     = cvt8(A0, A1);
        *(bf16x8*)&as[arow][acol + 8] = cvt8(A2, A3);
        __syncthreads();
        #pragma unroll
        for (int ks = 0; ks < 4; ++ks) {
            bf16x8 af = *(const bf16x8*)&xs[m0 + frow][ks*32 + koff];
            bf16x8 bf_ = *(const bf16x8*)&as[n0 + frow][ks*32 + koff];
            acc = __builtin_amdgcn_mfma_f32_16x16x32_bf16(af, bf_, acc, 0, 0, 0);
        }
        __syncthreads();
    };

    const int NT = DIN / 128;   // 32 (even)
    load(xA0,xA1,aA0,aA1,aA2,aA3, 0);
    for (int kt = 0; kt < NT; kt += 2) {
        load(xB0,xB1,aB0,aB1,aB2,aB3, kt + 1);
        consume(xA0,xA1,aA0,aA1,aA2,aA3);
        if (kt + 2 < NT) load(xA0,xA1,aA0,aA1,aA2,aA3, kt + 2);
        consume(xB0,xB1,aB0,aB1,aB2,aB3);
    }

    // row sumsq: lanes sharing (l>>4) hold the same x-row -> reduce low 4 bits
    ssq += __shfl_xor(ssq, 1);
    ssq += __shfl_xor(ssq, 2);
    ssq += __shfl_xor(ssq, 4);
    ssq += __shfl_xor(ssq, 8);
    if ((l & 15) == 0) rowss[w * 4 + (l >> 4)] = ssq;
    __syncthreads();
    if (t < 32) {
        float vn = fmaxf(sqrtf(rowss[t]), EPSF);
        rowss[t] = sinhf(vn) / vn;
    }
    __syncthreads();

    #pragma unroll
    for (int q = 0; q < 4; ++q) {
        const int row = m0 + (l >> 4) * 4 + q;
        s1[(size_t)(brow + row) * RNK + n0 + frow] = rowss[row] * acc[q];
    }
}

// ---------------------------------------------------------------------------
// KB: Gram partials Gpart[b] = (B-slice)^T (B-slice), plus B -> bf16 copy.
// 16 blocks x 256 j-rows. Plain stores, no atomics.
// ---------------------------------------------------------------------------
__global__ __launch_bounds__(512, 4)
void kb_gram(const float* __restrict__ Bw, __bf16* __restrict__ Bp,
             float* __restrict__ Gpart) {
    __shared__ __bf16 bs[256][72];   // 36.9 KB
    const int t = threadIdx.x;
    const int jb = blockIdx.x * 256;

    // stage + convert + write-back: thread t -> row j0=t>>1, cols (t&1)*32..+31
    {
        const int j0 = t >> 1, c0 = (t & 1) * 32;
        #pragma unroll
        for (int u = 0; u < 4; ++u) {
            f32x4 v0 = *(const f32x4*)&Bw[(size_t)(jb + j0) * RNK + c0 + 8*u];
            f32x4 v1 = *(const f32x4*)&Bw[(size_t)(jb + j0) * RNK + c0 + 8*u + 4];
            bf16x8 p = cvt8(v0, v1);
            *(bf16x8*)&bs[j0][c0 + 8*u] = p;
            *(bf16x8*)&Bp[(size_t)(jb + j0) * RNK + c0 + 8*u] = p;
        }
    }
    __syncthreads();

    // thread t owns cells (r = t&63, r' = (t>>6)*8 .. +7)
    const int r = t & 63, rp = (t >> 6) * 8;
    float acc[8] = {0,0,0,0,0,0,0,0};
    for (int j = 0; j < 256; ++j) {
        float s = (float)bs[j][r];
        bf16x8 v = *(const bf16x8*)&bs[j][rp];   // wave-uniform addr: broadcast
        #pragma unroll
        for (int u = 0; u < 8; ++u) acc[u] += s * (float)v[u];
    }
    #pragma unroll
    for (int u = 0; u < 8; ++u)
        Gpart[(size_t)blockIdx.x * 4096 + r * 64 + rp + u] = acc[u];
}

// C0: sum 16 Gram partials -> G (single block)
__global__ void kc0_sum(const float* __restrict__ Gpart, float* __restrict__ G) {
    const int t = threadIdx.x;   // 256 thr, 16 f32 each
    #pragma unroll
    for (int v = 0; v < 4; ++v) {
        f32x4 a = {0.f, 0.f, 0.f, 0.f};
        for (int b = 0; b < 16; ++b)
            a += *(const f32x4*)&Gpart[(size_t)b * 4096 + t * 16 + v * 4];
        *(f32x4*)&G[t * 16 + v * 4] = a;
    }
}

// ---------------------------------------------------------------------------
// KC: per-row r2 = s1^T G s1 ; g = 0.25*acosh(max(sqrt(1+r2),1+eps))/max(r,eps)
//     s1p = bf16(g * s1).  One wave per row, 8 rows/block, 2048 blocks.
// ---------------------------------------------------------------------------
__global__ __launch_bounds__(512, 4)
void kc_scale(const float* __restrict__ s1, const float* __restrict__ G,
              __bf16* __restrict__ s1p) {
    __shared__ float Gs[64][64];   // 16 KB
    __shared__ float sr[8][64];
    const int t = threadIdx.x, l = t & 63, w = t >> 6;

    {   // stage G: 4096 f32 / 512 thr = 8 each
        float* gf = &Gs[0][0];
        *(f32x4*)&gf[t * 8]     = *(const f32x4*)&G[t * 8];
        *(f32x4*)&gf[t * 8 + 4] = *(const f32x4*)&G[t * 8 + 4];
    }
    const int row = blockIdx.x * 8 + w;
    const float a = s1[(size_t)row * RNK + l];
    sr[w][l] = a;
    __syncthreads();

    float y = 0.f;
    #pragma unroll 8
    for (int r = 0; r < 64; ++r) y += Gs[r][l] * sr[w][r];

    float q = a * y;
    q += __shfl_xor(q, 1);  q += __shfl_xor(q, 2);  q += __shfl_xor(q, 4);
    q += __shfl_xor(q, 8);  q += __shfl_xor(q, 16); q += __shfl_xor(q, 32);

    const float r2 = q;
    const float rn = sqrtf(r2);
    const float g = 0.25f * acoshf(fmaxf(sqrtf(1.f + r2), 1.f + EPSF))
                          / fmaxf(rn, EPSF);
    s1p[(size_t)row * RNK + l] = (__bf16)(g * a);
}

// ---------------------------------------------------------------------------
// K2: out = s1p @ Bp^T.  Pure GEMM, K=64 (2 MFMA steps), no loop.
// 64x64 tiles, 16384 blocks (4/CU), 8 waves = 4m x 2n, wave: 16r x 32c.
// ---------------------------------------------------------------------------
__global__ __launch_bounds__(512, 4)
void k2_gemm2(const __bf16* __restrict__ s1p, const __bf16* __restrict__ Bp,
              float* __restrict__ out) {
    __shared__ __bf16 ss[64][72];
    __shared__ __bf16 bsh[64][72];
    const int t = threadIdx.x, l = t & 63, w = t >> 6;
    const int rt = blockIdx.x >> 6;     // 256 row tiles
    const int ct = blockIdx.x & 63;     // 64 col tiles
    const int brow = rt * 64, bcol = ct * 64;

    {   // stage both tiles: thread t -> row t>>3, col (t&7)*8 (16 B each)
        const int row = t >> 3, c = (t & 7) * 8;
        *(bf16x8*)&ss[row][c]  = *(const bf16x8*)&s1p[(size_t)(brow + row) * RNK + c];
        *(bf16x8*)&bsh[row][c] = *(const bf16x8*)&Bp[(size_t)(bcol + row) * RNK + c];
    }
    __syncthreads();

    const int m0 = (w & 3) * 16;
    const int n0 = (w >> 2) * 32;
    const int frow = l & 15;
    const int koff = (l >> 4) * 8;

    f32x4 a0 = {0.f,0.f,0.f,0.f}, a1 = {0.f,0.f,0.f,0.f};
    #pragma unroll
    for (int ks = 0; ks < 2; ++ks) {
        bf16x8 af = *(const bf16x8*)&ss[m0 + frow][ks*32 + koff];
        bf16x8 b0 = *(const bf16x8*)&bsh[n0 + frow][ks*32 + koff];
        bf16x8 b1 = *(const bf16x8*)&bsh[n0 + 16 + frow][ks*32 + koff];
        a0 = __builtin_amdgcn_mfma_f32_16x16x32_bf16(af, b0, a0, 0, 0, 0);
        a1 = __builtin_amdgcn_mfma_f32_16x16x32_bf16(af, b1, a1, 0, 0, 0);
    }

    #pragma unroll
    for (int q = 0; q < 4; ++q) {
        const int row = m0 + (l >> 4) * 4 + q;
        const size_t ob = (size_t)(brow + row) * DOUT + bcol;
        out[ob + n0 + frow]      = a0[q];
        out[ob + n0 + 16 + frow] = a1[q];
    }
}

extern "C" void kernel_launch(void* const* d_in, const int* in_sizes, int n_in,
                              void* d_out, int out_size, void* d_ws, size_t ws_size,
                              hipStream_t stream) {
    const float* x  = (const float*)d_in[0];   // (16384, 4096)
    const float* Aw = (const float*)d_in[1];   // (64, 4096)
    const float* Bw = (const float*)d_in[2];   // (4096, 64)
    float* out = (float*)d_out;

    char* ws = (char*)d_ws;
    float*  s1    = (float*)(ws);                       // 4 MB
    __bf16* s1p   = (__bf16*)(ws + 4194304);            // 2 MB
    __bf16* Bp    = (__bf16*)(ws + 6291456);            // 512 KB
    float*  Gpart = (float*)(ws + 6815744);             // 256 KB
    float*  G     = (float*)(ws + 7077888);             // 16 KB

    k1_expmap_gemm1<<<NROWS / 32, 512, 0, stream>>>(x, Aw, s1);
    kb_gram<<<16, 512, 0, stream>>>(Bw, Bp, Gpart);
    kc0_sum<<<1, 256, 0, stream>>>(Gpart, G);
    kc_scale<<<NROWS / 8, 512, 0, stream>>>(s1, G, s1p);
    k2_gemm2<<<16384, 512, 0, stream>>>(s1p, Bp, out);
}